// Round 2
// baseline (121.718 us; speedup 1.0000x reference)
//
#include <hip/hip_runtime.h>
#include <hip/hip_bf16.h>

// Problem: B=32, S=512, P=512, D=768
//   M = B*S = 16384 tokens, N = P = 512 prototypes, K = D = 768
// out[0 .. M*N)            = distances  ||x_m - p_n||^2  (fp32)
// out[M*N .. M*N + N*K)    = prototypes (fp32 passthrough)
//
// R7 = R6 with the launch-config bug fixed: the 64x256 block decomposition
// needs 512 blocks (256 M-stripes x 2 N-halves); R6 still launched 256, so
// half the tiles were never computed (absmax 1952 = memset-0 tiles).
//
// Structure (unchanged from R6):
//   - A staged in K-chunks of 128 (LDS 2x17KB dbuf = 34.8 KB): global->reg
//     loads for chunk k+1 issue BEFORE chunk k's 128 MFMAs, convert+ds_write
//     after (T14 async-stage split). One barrier per chunk.
//   - Block = 64 rows x 256 cols, 8 waves of 64x32 each.
//   - Grid 512 = 2 blocks/CU (launch_bounds(512,4), acc[4][2]=32 VGPR).
//   - XCD-chunked swizzle: the two N-halves of one stripe land adjacent on
//     the same XCD -> second A-stripe read is L2-hot.

#define M_TOK 16384
#define N_PROT 512
#define K_DIM 768
#define BKC 128              // K-chunk staged in LDS
#define NKC (K_DIM / BKC)    // 6
#define NSK (K_DIM / 32)     // 24 MFMA k-steps
#define ASTR 136             // LDS row stride (bf16 units): 128 + 8 pad -> 2-way only

typedef __attribute__((ext_vector_type(4))) float f32x4;
typedef __attribute__((ext_vector_type(8))) short bf16x8;

__device__ inline unsigned short f2bf(float f) {
    unsigned int u = __float_as_uint(f);
    u += 0x7fffu + ((u >> 16) & 1u);
    return (unsigned short)(u >> 16);
}

// One wave per prototype row: bf16 convert + ||p||^2 + fp32 passthrough copy.
__global__ __launch_bounds__(256) void prep_b(
    const float* __restrict__ p,
    unsigned short* __restrict__ b_bf, float* __restrict__ p_sq,
    float* __restrict__ proto_out)
{
    const int row  = blockIdx.x * 4 + (threadIdx.x >> 6);
    const int lane = threadIdx.x & 63;

    const float4* src4 = (const float4*)(p + (size_t)row * K_DIM);
    unsigned short* dst = b_bf + (size_t)row * K_DIM;
    float4* pout4 = (float4*)(proto_out + (size_t)row * K_DIM);

    float ssum = 0.0f;
#pragma unroll
    for (int j = 0; j < 3; ++j) {
        const int idx = lane + j * 64;
        float4 v = src4[idx];
        ssum += v.x * v.x + v.y * v.y + v.z * v.z + v.w * v.w;
        ushort4 b;
        b.x = f2bf(v.x); b.y = f2bf(v.y); b.z = f2bf(v.z); b.w = f2bf(v.w);
        ((ushort4*)dst)[idx] = b;
        pout4[idx] = v;
    }
#pragma unroll
    for (int off = 32; off > 0; off >>= 1) ssum += __shfl_down(ssum, off);
    if (lane == 0) p_sq[row] = ssum;
}

__global__ __launch_bounds__(512, 4) void dist_main(
    const float* __restrict__ X,             // [M,K] fp32 tokens
    const unsigned short* __restrict__ Bb,   // [N,K] bf16 prototypes (ws)
    const float* __restrict__ p_sq,          // [N] fp32
    float* __restrict__ out)                 // [M,N] fp32 distances
{
    __shared__ unsigned short lds_a[2][64 * ASTR];   // 2 x 17408 B = 34816 B
    __shared__ float lds_xsq[64];

    // ---- block mapping: XCD-chunked swizzle, pair-adjacent N-halves ----
    // hw block b -> XCD b%8 (dispatch heuristic). logical id walks 64-runs
    // per XCD; consecutive logical ids (two N-halves of a stripe) share XCD.
    const int bid     = blockIdx.x;              // 0..511
    const int logical = (bid & 7) * 64 + (bid >> 3);   // bijective over 0..511
    const int ms = logical >> 1;                 // M-stripe 0..255
    const int nh = logical & 1;                  // N half
    const int bm = ms << 6;
    const int bn = nh << 8;

    const int tid  = threadIdx.x;
    const int wave = tid >> 6;           // 0..7
    const int lane = tid & 63;
    const int wn   = bn + (wave << 5);   // wave's 32-col slice of N
    const int quad = lane >> 4;          // 0..3
    const int l16  = lane & 15;

    // ---- staging mapping: 512 thr stage a 64x128 fp32 chunk (4 float4/thr) ----
    const int ar = tid >> 3;             // row 0..63
    const int ac = tid & 7;              // float4 col base
    const float* aptr = X + (size_t)(bm + ar) * K_DIM + ac * 4;

    float asq = 0.0f;

    // prologue: stage chunk 0
    {
        float4 v0 = *(const float4*)(aptr);
        float4 v1 = *(const float4*)(aptr + 32);
        float4 v2 = *(const float4*)(aptr + 64);
        float4 v3 = *(const float4*)(aptr + 96);
        float4 vv[4] = {v0, v1, v2, v3};
#pragma unroll
        for (int j = 0; j < 4; ++j) {
            float4 v = vv[j];
            asq += v.x * v.x + v.y * v.y + v.z * v.z + v.w * v.w;
            ushort4 u;
            u.x = f2bf(v.x); u.y = f2bf(v.y); u.z = f2bf(v.z); u.w = f2bf(v.w);
            *(ushort4*)&lds_a[0][ar * ASTR + (ac + 8 * j) * 4] = u;
        }
    }
    __syncthreads();

    // ---- B fragment pipeline: global->VGPR, L2-hot, 1 k-step ahead ----
    const unsigned short* bp = Bb + (size_t)(wn + l16) * K_DIM + quad * 8;

    bf16x8 bcur0 = *(const bf16x8*)(bp);
    bf16x8 bcur1 = *(const bf16x8*)(bp + 16 * K_DIM);
    bf16x8 bnxt0, bnxt1;

    const f32x4 zero = {0.0f, 0.0f, 0.0f, 0.0f};
    f32x4 acc[4][2];
#pragma unroll
    for (int mt = 0; mt < 4; ++mt) {
        acc[mt][0] = zero; acc[mt][1] = zero;
    }

    for (int kc = 0; kc < NKC; ++kc) {
        // issue next A-chunk global loads early (hide under this chunk's MFMAs)
        float4 s0, s1, s2, s3;
        if (kc + 1 < NKC) {
            const float* ap = aptr + (kc + 1) * BKC;
            s0 = *(const float4*)(ap);
            s1 = *(const float4*)(ap + 32);
            s2 = *(const float4*)(ap + 64);
            s3 = *(const float4*)(ap + 96);
        }

#pragma unroll
        for (int s = 0; s < 4; ++s) {
            const int kk = kc * 4 + s;
            if (kk + 1 < NSK) {              // uniform scalar branch
                const int kn = (kk + 1) * 32;
                bnxt0 = *(const bf16x8*)(bp + kn);
                bnxt1 = *(const bf16x8*)(bp + 16 * K_DIM + kn);
            }

            bf16x8 af[4];
#pragma unroll
            for (int mt = 0; mt < 4; ++mt)
                af[mt] = *(const bf16x8*)&lds_a[kc & 1]
                    [(mt * 16 + l16) * ASTR + s * 32 + quad * 8];

#pragma unroll
            for (int mt = 0; mt < 4; ++mt) {
                acc[mt][0] = __builtin_amdgcn_mfma_f32_16x16x32_bf16(
                    af[mt], bcur0, acc[mt][0], 0, 0, 0);
                acc[mt][1] = __builtin_amdgcn_mfma_f32_16x16x32_bf16(
                    af[mt], bcur1, acc[mt][1], 0, 0, 0);
            }
            bcur0 = bnxt0; bcur1 = bnxt1;
        }

        // convert + write next chunk into the other buffer, then one barrier
        if (kc + 1 < NKC) {
            unsigned short* aw = &lds_a[(kc + 1) & 1][ar * ASTR + ac * 4];
            float4 vv[4] = {s0, s1, s2, s3};
#pragma unroll
            for (int j = 0; j < 4; ++j) {
                float4 v = vv[j];
                asq += v.x * v.x + v.y * v.y + v.z * v.z + v.w * v.w;
                ushort4 u;
                u.x = f2bf(v.x); u.y = f2bf(v.y); u.z = f2bf(v.z); u.w = f2bf(v.w);
                *(ushort4*)(aw + 8 * j * 4) = u;
            }
        }
        __syncthreads();
    }

    // ---- x_sq: reduce over the 8 staging threads of each row ----
#pragma unroll
    for (int off = 1; off < 8; off <<= 1) asq += __shfl_xor(asq, off);
    if (ac == 0) lds_xsq[ar] = asq;
    __syncthreads();

    // ---- epilogue: C/D layout col = lane&15, row = quad*4 + i ----
    float ps0 = p_sq[wn + l16];
    float ps1 = p_sq[wn + 16 + l16];

#pragma unroll
    for (int mt = 0; mt < 4; ++mt) {
#pragma unroll
        for (int i = 0; i < 4; ++i) {
            const int lr = mt * 16 + quad * 4 + i;   // local row 0..63
            const float xs = lds_xsq[lr];
            float* orow = out + (size_t)(bm + lr) * N_PROT + wn + l16;
            orow[0]  = xs + ps0 - 2.0f * acc[mt][0][i];
            orow[16] = xs + ps1 - 2.0f * acc[mt][1][i];
        }
    }
}

extern "C" void kernel_launch(void* const* d_in, const int* in_sizes, int n_in,
                              void* d_out, int out_size, void* d_ws, size_t ws_size,
                              hipStream_t stream) {
    const float* inputs = (const float*)d_in[0];   // [32,512,768] fp32
    const float* protos = (const float*)d_in[1];   // [512,768]    fp32
    float* out = (float*)d_out;
    float* proto_out = out + (size_t)M_TOK * N_PROT;   // second tuple element

    // ws layout: b_bf 512*768*2 = 786,432 B ; p_sq 512*4 = 2,048 B
    char* ws = (char*)d_ws;
    unsigned short* b_bf = (unsigned short*)ws;
    float* p_sq = (float*)(ws + 786432);

    prep_b<<<128, 256, 0, stream>>>(protos, b_bf, p_sq, proto_out);
    // 256 M-stripes x 2 N-halves = 512 blocks (R6 bug: launched 256)
    dist_main<<<2 * (M_TOK / 64), 512, 0, stream>>>(inputs, b_bf, p_sq, out);
}